// Round 4
// baseline (81.708 us; speedup 1.0000x reference)
//
#include <hip/hip_runtime.h>
#include <hip/hip_bf16.h>
#include <math.h>

// Problem constants (match reference file)
constexpr int kL = 10;              // NUM_LEVEL
constexpr int kE = 64;              // EMB_SIZE
constexpr int kTokens = 64 * 1024;  // B * S

constexpr int BLOCK = 256;
constexpr int TOKENS_PER_BLOCK = BLOCK / 8;   // 8 lanes per token

typedef unsigned short ushort8v __attribute__((ext_vector_type(8)));
typedef float          float4v  __attribute__((ext_vector_type(4)));

__device__ __forceinline__ float b2f(unsigned short u) {
    union { unsigned int i; float f; } v;
    v.i = ((unsigned int)u) << 16;
    return v.f;
}

__device__ __forceinline__ bool sane_bf16(float v) {
    return isfinite(v) && (fabsf(v) < 64.f);
}

__global__ __launch_bounds__(BLOCK) void kc_route_kernel(
    const int* __restrict__ croutes,            // [T, L] int32
    const void* __restrict__ emb_raw,           // [10000, 64] bf16 OR fp32 (detected)
    const void* __restrict__ wts_raw,           // [L] bf16 OR fp32 (detected)
    float* __restrict__ out)                    // [T, E] fp32
{
    const int tid   = blockIdx.x * BLOCK + threadIdx.x;
    const int token = tid >> 3;
    const int sub   = tid & 7;
    if (token >= kTokens) return;

    // --- dtype detection (wave-uniform, data-stable; OOB-safe both ways) ---
    // A true-bf16 N(0,1) tensor always passes |v|<64 & finite. A fp32 buffer
    // misread as bf16 has random-exponent garbage in its low-half words:
    // P(pass) ~ 0.52 per word -> misclassification ~1e-9 over 64/10 words.
    const unsigned short* e16 = (const unsigned short*)emb_raw;
    bool emb_bf16 = true;
#pragma unroll
    for (int i = 0; i < 64; ++i) emb_bf16 = emb_bf16 && sane_bf16(b2f(e16[i]));

    float wv[kL];
    {
        const unsigned short* w16 = (const unsigned short*)wts_raw;
        bool wts_bf16 = true;
#pragma unroll
        for (int l = 0; l < kL; ++l) {
            wv[l] = b2f(w16[l]);
            wts_bf16 = wts_bf16 && sane_bf16(wv[l]);
        }
        if (!wts_bf16) {
            const float* w32 = (const float*)wts_raw;
#pragma unroll
            for (int l = 0; l < kL; ++l) wv[l] = w32[l];
        }
    }

    // --- indices + masked logits ------------------------------------------
    int   idx[kL];
    float logit[kL];
#pragma unroll
    for (int l = 0; l < kL; ++l) {
        idx[l] = croutes[(size_t)token * kL + l];
        // level available iff croutes != -2 (related_concepts != 0)
        logit[l] = (idx[l] != -2) ? wv[l] : -__builtin_inff();
    }

    // --- softmax over levels ----------------------------------------------
    float m = logit[0];
#pragma unroll
    for (int l = 1; l < kL; ++l) m = fmaxf(m, logit[l]);
    float a[kL];
    float s = 0.f;
#pragma unroll
    for (int l = 0; l < kL; ++l) { a[l] = __expf(logit[l] - m); s += a[l]; }
    const float inv = 1.f / s;

    // --- gather + weighted accumulate (8 fp32 outputs per lane) -----------
    float acc[8];
#pragma unroll
    for (int i = 0; i < 8; ++i) acc[i] = 0.f;

    const int e0 = sub * 8;
    if (emb_bf16) {
        const __hip_bfloat16* emb = (const __hip_bfloat16*)emb_raw;
#pragma unroll
        for (int l = 0; l < kL; ++l) {
            const int c  = idx[l];
            // c==-2: masked (alpha 0); c==-1: zero row in the concat table.
            const float al = (c >= 0) ? a[l] * inv : 0.f;
            const int   cc = (c >= 0) ? c : 0;
            const ushort8v u = *reinterpret_cast<const ushort8v*>(
                emb + (size_t)cc * kE + e0);     // 16 B aligned vector load
#pragma unroll
            for (int i = 0; i < 8; ++i)
                acc[i] = fmaf(al, b2f(u[i]), acc[i]);
        }
    } else {
        const float* emb = (const float*)emb_raw;
#pragma unroll
        for (int l = 0; l < kL; ++l) {
            const int c  = idx[l];
            const float al = (c >= 0) ? a[l] * inv : 0.f;
            const int   cc = (c >= 0) ? c : 0;
            const float4v u0 = *reinterpret_cast<const float4v*>(
                emb + (size_t)cc * kE + e0);
            const float4v u1 = *reinterpret_cast<const float4v*>(
                emb + (size_t)cc * kE + e0 + 4);
#pragma unroll
            for (int i = 0; i < 4; ++i) {
                acc[i]     = fmaf(al, u0[i], acc[i]);
                acc[i + 4] = fmaf(al, u1[i], acc[i + 4]);
            }
        }
    }

    // --- store 32 B fp32, coalesced ---------------------------------------
    float4v o0, o1;
#pragma unroll
    for (int i = 0; i < 4; ++i) { o0[i] = acc[i]; o1[i] = acc[i + 4]; }
    float* op = out + (size_t)token * kE + e0;
    *reinterpret_cast<float4v*>(op)     = o0;
    *reinterpret_cast<float4v*>(op + 4) = o1;
}

extern "C" void kernel_launch(void* const* d_in, const int* in_sizes, int n_in,
                              void* d_out, int out_size, void* d_ws, size_t ws_size,
                              hipStream_t stream) {
    const int*  croutes = (const int*)d_in[0];   // [B,S,L] int32
    // d_in[1] = tailcs — unused by the reference computation
    const void* emb     = (const void*)d_in[2];  // [10000,64] bf16 or fp32
    const void* wts     = (const void*)d_in[3];  // [10] bf16 or fp32
    float*      out     = (float*)d_out;         // [B,S,E] fp32

    const int grid = (kTokens + TOKENS_PER_BLOCK - 1) / TOKENS_PER_BLOCK; // 2048
    kc_route_kernel<<<grid, BLOCK, 0, stream>>>(croutes, emb, wts, out);
}